// Round 4
// baseline (422.090 us; speedup 1.0000x reference)
//
#include <hip/hip_runtime.h>
#include <hip/hip_bf16.h>

// SNN EventProp LIF forward, 2 layers: 784 -> 1024 -> 256, T=100, B=256.
//
// Layer 1 (dominant, L2-BW-bound at ~4 GB of weight gathers): FULLY FUSED.
// One block per batch b; thread owns 4 contiguous cols (256*4 = 1024). Per
// step t: gather W1T rows of the active x entries (float4, L2-hot 3.2 MB
// table), LIF update in registers, write uint8 spike row. The x row for t+1
// is prefetched into registers during t's gather; active lists double-buffer
// in LDS. Eliminates the C1 buffer (100 MB write + 100 MB read) and the
// separate scan kernel. Per-step work is 39*4KB = 160 KB of L2 reads per
// block -> BW-bound, so 1 wave/SIMD occupancy is enough (unlike layer 2,
// where per-step work is tiny and the same fusion was a measured regression).
//
// Layer 2 (tiny: spike rate ~4.4 sigma): one WAVE per row, ballot
// compaction, gather W2T rows (1 MB, L2-hot), then a separate scan kernel.
//
// ALPHA=0.8f, BETA=0.95f, 1-BETA=0.05f (exact float32 of the Python consts).

#define ALPHA_F 0.8f
#define BETA_F 0.95f
#define ONE_MINUS_BETA_F 0.05f

// WT[k*N + n] = W[n*K + k].  W: [N,K] row-major.
__global__ __launch_bounds__(256) void transpose_nt(const float* __restrict__ W,
                                                    float* __restrict__ WT,
                                                    int N, int K) {
    __shared__ float tile[32][33];
    const int k0 = blockIdx.x * 32, n0 = blockIdx.y * 32;
    const int tx = threadIdx.x & 31, ty = threadIdx.x >> 5;   // 32 x 8
#pragma unroll
    for (int r = 0; r < 4; ++r) {
        int n = n0 + ty + r * 8, k = k0 + tx;
        if (n < N && k < K) tile[ty + r * 8][tx] = W[(size_t)n * K + k];
    }
    __syncthreads();
#pragma unroll
    for (int r = 0; r < 4; ++r) {
        int k = k0 + ty + r * 8, n = n0 + tx;
        if (k < K && n < N) WT[(size_t)k * N + n] = tile[tx][ty + r * 8];
    }
}

// Fused layer 1: grid = 256 (one block per batch b), 256 threads.
// S1 layout: S1[t*262144 + b*1024 + n], uint8 spikes, rows t=0..98.
__global__ __launch_bounds__(256) void layer1_fused(const float* __restrict__ x,
                                                    const float* __restrict__ W1T,
                                                    unsigned char* __restrict__ S1) {
    __shared__ unsigned short list[2][800];
    __shared__ int cnt[2];
    const int b = blockIdx.x;
    const int tid = threadIdx.x;

    // t = 0 spike row is zero
    uchar4 z4 = {0, 0, 0, 0};
    *(uchar4*)(S1 + (size_t)b * 1024 + tid * 4) = z4;

    if (tid == 0) { cnt[0] = 0; cnt[1] = 0; }
    __syncthreads();
    // prologue: compact x row 0 into list[0]
    if (tid < 196) {
        float4 v = *(const float4*)(x + (size_t)b * 784 + tid * 4);
        if (v.x != 0.0f) list[0][atomicAdd(&cnt[0], 1)] = (unsigned short)(tid * 4 + 0);
        if (v.y != 0.0f) list[0][atomicAdd(&cnt[0], 1)] = (unsigned short)(tid * 4 + 1);
        if (v.z != 0.0f) list[0][atomicAdd(&cnt[0], 1)] = (unsigned short)(tid * 4 + 2);
        if (v.w != 0.0f) list[0][atomicAdd(&cnt[0], 1)] = (unsigned short)(tid * 4 + 3);
    }
    __syncthreads();

    float4 I = {0, 0, 0, 0}, V = {0, 0, 0, 0};
    const float* wbase = W1T + tid * 4;

    for (int t = 1; t <= 98; ++t) {
        const int cur = (t - 1) & 1, nxt = t & 1;
        // prefetch x row t (consumed by steps t+1); hidden behind the gather
        float4 xv;
        const bool ldx = (t < 98) && (tid < 196);
        if (ldx) xv = *(const float4*)(x + ((size_t)t * 256 + b) * 784 + tid * 4);

        const int n = cnt[cur];
        float4 acc = {0, 0, 0, 0};
        int i = 0;
        for (; i + 8 <= n; i += 8) {   // 8-deep independent dwordx4 gathers
            float4 w0 = *(const float4*)(wbase + (size_t)list[cur][i + 0] * 1024);
            float4 w1 = *(const float4*)(wbase + (size_t)list[cur][i + 1] * 1024);
            float4 w2 = *(const float4*)(wbase + (size_t)list[cur][i + 2] * 1024);
            float4 w3 = *(const float4*)(wbase + (size_t)list[cur][i + 3] * 1024);
            float4 w4 = *(const float4*)(wbase + (size_t)list[cur][i + 4] * 1024);
            float4 w5 = *(const float4*)(wbase + (size_t)list[cur][i + 5] * 1024);
            float4 w6 = *(const float4*)(wbase + (size_t)list[cur][i + 6] * 1024);
            float4 w7 = *(const float4*)(wbase + (size_t)list[cur][i + 7] * 1024);
            acc.x += ((w0.x + w1.x) + (w2.x + w3.x)) + ((w4.x + w5.x) + (w6.x + w7.x));
            acc.y += ((w0.y + w1.y) + (w2.y + w3.y)) + ((w4.y + w5.y) + (w6.y + w7.y));
            acc.z += ((w0.z + w1.z) + (w2.z + w3.z)) + ((w4.z + w5.z) + (w6.z + w7.z));
            acc.w += ((w0.w + w1.w) + (w2.w + w3.w)) + ((w4.w + w5.w) + (w6.w + w7.w));
        }
        for (; i < n; ++i) {
            float4 w0 = *(const float4*)(wbase + (size_t)list[cur][i] * 1024);
            acc.x += w0.x; acc.y += w0.y; acc.z += w0.z; acc.w += w0.w;
        }

        // LIF update (4 cols per thread)
        I.x = ALPHA_F * I.x + acc.x;
        I.y = ALPHA_F * I.y + acc.y;
        I.z = ALPHA_F * I.z + acc.z;
        I.w = ALPHA_F * I.w + acc.w;
        float vx = BETA_F * V.x + ONE_MINUS_BETA_F * I.x;
        float vy = BETA_F * V.y + ONE_MINUS_BETA_F * I.y;
        float vz = BETA_F * V.z + ONE_MINUS_BETA_F * I.z;
        float vw = BETA_F * V.w + ONE_MINUS_BETA_F * I.w;
        uchar4 s;
        s.x = vx > 1.0f; s.y = vy > 1.0f; s.z = vz > 1.0f; s.w = vw > 1.0f;
        V.x = s.x ? 0.0f : vx; V.y = s.y ? 0.0f : vy;
        V.z = s.z ? 0.0f : vz; V.w = s.w ? 0.0f : vw;
        *(uchar4*)(S1 + (size_t)t * 262144 + (size_t)b * 1024 + tid * 4) = s;

        // build next active list (safe: list[nxt]/cnt[nxt] last read 2 iters ago)
        if (tid == 0) cnt[nxt] = 0;
        __syncthreads();
        if (ldx) {
            if (xv.x != 0.0f) list[nxt][atomicAdd(&cnt[nxt], 1)] = (unsigned short)(tid * 4 + 0);
            if (xv.y != 0.0f) list[nxt][atomicAdd(&cnt[nxt], 1)] = (unsigned short)(tid * 4 + 1);
            if (xv.z != 0.0f) list[nxt][atomicAdd(&cnt[nxt], 1)] = (unsigned short)(tid * 4 + 2);
            if (xv.w != 0.0f) list[nxt][atomicAdd(&cnt[nxt], 1)] = (unsigned short)(tid * 4 + 3);
        }
        __syncthreads();
    }
}

// Layer-2 gather: one wave per row r of S1 (25344 rows), 4 rows per block.
// Lane reads 16 bytes of the spike row, bytes->bits via multiply trick,
// ballot-broadcast actives, gather W2T rows (lane owns 4 contiguous cols).
__global__ __launch_bounds__(256) void sparse2(const unsigned char* __restrict__ S1,
                                               const float* __restrict__ W2T,
                                               float* __restrict__ C2) {
    const int r = blockIdx.x * 4 + (threadIdx.x >> 6);
    const int lane = threadIdx.x & 63;
    uint4 sv = *(const uint4*)(S1 + (size_t)r * 1024 + lane * 16);
    // bytes are exactly 0/1: (v * 0x01020408) >> 24 packs them into 4 bits
    unsigned m16 = ((sv.x * 0x01020408u) >> 24) |
                   (((sv.y * 0x01020408u) >> 24) << 4) |
                   (((sv.z * 0x01020408u) >> 24) << 8) |
                   (((sv.w * 0x01020408u) >> 24) << 12);
    float4 acc = {0, 0, 0, 0};
#pragma unroll 1
    for (int j = 0; j < 16; ++j) {
        unsigned long long bm = __ballot((m16 >> j) & 1u);
        while (bm) {
            int L = __ffsll(bm) - 1;
            bm &= bm - 1;
            int k = L * 16 + j;
            float4 w = *(const float4*)(W2T + (size_t)k * 256 + lane * 4);
            acc.x += w.x; acc.y += w.y; acc.z += w.z; acc.w += w.w;
        }
    }
    *(float4*)(C2 + (size_t)r * 256 + lane * 4) = acc;
}

// Layer-2 scan: one thread per (b,n2), idx in [0, 65536). C2 rows t=0..98.
__global__ __launch_bounds__(256) void scan2(const float* __restrict__ C2,
                                             float* __restrict__ out) {
    const int idx = blockIdx.x * 256 + threadIdx.x;
    out[idx] = 0.0f;                                   // t = 0
    float I = 0.0f, V = 0.0f;
    for (int t = 1; t <= 99; ++t) {
        float c = C2[(size_t)(t - 1) * 65536 + idx];
        I = ALPHA_F * I + c;
        float Vp = BETA_F * V + ONE_MINUS_BETA_F * I;
        float s = (Vp > 1.0f) ? 1.0f : 0.0f;
        V = (1.0f - s) * Vp;
        out[(size_t)t * 65536 + idx] = s;
    }
}

extern "C" void kernel_launch(void* const* d_in, const int* in_sizes, int n_in,
                              void* d_out, int out_size, void* d_ws, size_t ws_size,
                              hipStream_t stream) {
    const float* x  = (const float*)d_in[0];   // [100,256,784] binary
    const float* W1 = (const float*)d_in[1];   // [1024,784]
    const float* W2 = (const float*)d_in[2];   // [256,1024]
    float* out = (float*)d_out;                // [100,256,256]

    // Workspace (~56 MB):
    //   S1u8 : 25344*1024   =  25,952,256 B
    //   C2   : 25344*256*4  =  25,952,256 B
    //   W1T  : 784*1024*4   =   3,211,264 B
    //   W2T  : 1024*256*4   =   1,048,576 B
    char* ws = (char*)d_ws;
    unsigned char* S1 = (unsigned char*)ws;
    float* C2  = (float*)(ws + (size_t)25344 * 1024);
    float* W1T = (float*)(ws + (size_t)25344 * 1024 + (size_t)25344 * 256 * 4);
    float* W2T = W1T + (size_t)784 * 1024;

    transpose_nt<<<dim3(25, 32), 256, 0, stream>>>(W1, W1T, 1024, 784);
    transpose_nt<<<dim3(32, 8), 256, 0, stream>>>(W2, W2T, 256, 1024);

    layer1_fused<<<256, 256, 0, stream>>>(x, W1T, S1);
    sparse2<<<25344 / 4, 256, 0, stream>>>(S1, W2T, C2);
    scan2<<<65536 / 256, 256, 0, stream>>>(C2, out);
}

// Round 5
// 297.332 us; speedup vs baseline: 1.4196x; 1.4196x over previous
//
#include <hip/hip_runtime.h>
#include <hip/hip_bf16.h>

// SNN EventProp LIF forward, 2 layers: 784 -> 1024 -> 256, T=100, B=256.
//
// Structure: LIF current I is LINEAR in the matmul results -> all T matmuls
// of a layer collapse into one batched sparse op + per-(b,n) streaming scan.
// Both matmul inputs are BINARY spikes (x ~5%; layer-1 spikes ~4.4 sigma
// rare), so each "GEMM" is a sparse gather-ADD of weight rows (fp32-exact).
//
// HARD-WON RULE (rounds 3+4): do NOT fuse the serial t-loop into the gather
// kernels — grid collapses to 1 wave/SIMD and goes latency-bound (measured
// 2x regressions both times). Gathers parallelize over all rows; scans are
// separate pure-streaming kernels with >=4 waves/SIMD.
//
//   transpose W1 -> W1T [784,1024], W2 -> W2T [1024,256]
//   sparse1 : C1[25088,1024] += W1T rows of active x entries
//             (ballot-compaction, no atomics; 8-deep float4 gather ILP)
//   scan1   : S1u8[25344,1024] spikes (t=0 zeroed); scalar, 4 waves/SIMD
//   sparse2 : C2[25344,256], one wave per row, ballot broadcast
//   scan2   : out[100,256,256] (t=0 zero + t=1..99)
//
// ALPHA=0.8f, BETA=0.95f, 1-BETA=0.05f (exact float32 of the Python consts).

#define ALPHA_F 0.8f
#define BETA_F 0.95f
#define ONE_MINUS_BETA_F 0.05f

// WT[k*N + n] = W[n*K + k].  W: [N,K] row-major.
__global__ __launch_bounds__(256) void transpose_nt(const float* __restrict__ W,
                                                    float* __restrict__ WT,
                                                    int N, int K) {
    __shared__ float tile[32][33];
    const int k0 = blockIdx.x * 32, n0 = blockIdx.y * 32;
    const int tx = threadIdx.x & 31, ty = threadIdx.x >> 5;   // 32 x 8
#pragma unroll
    for (int r = 0; r < 4; ++r) {
        int n = n0 + ty + r * 8, k = k0 + tx;
        if (n < N && k < K) tile[ty + r * 8][tx] = W[(size_t)n * K + k];
    }
    __syncthreads();
#pragma unroll
    for (int r = 0; r < 4; ++r) {
        int k = k0 + ty + r * 8, n = n0 + tx;
        if (k < K && n < N) WT[(size_t)k * N + n] = tile[tx][ty + r * 8];
    }
}

// Layer-1 sparse accumulate. One block per row r = t*256+b, t=0..97.
// Compaction: wave w owns x[row, w*196 .. w*196+195]; lanes 0..48 read one
// float4 each, build 4 flags, then ballot+popc prefix -> contiguous LDS list
// with NO atomics. Gather: thread owns 4 contiguous cols, dwordx4 loads.
__global__ __launch_bounds__(256) void sparse1(const float* __restrict__ x,
                                               const float* __restrict__ W1T,
                                               float* __restrict__ C1) {
    __shared__ unsigned short list[784];
    __shared__ int cnt[4];
    const int tid = threadIdx.x;
    const int row = blockIdx.x;
    const int wv = tid >> 6, lane = tid & 63;

    // ---- compaction (no atomics) ----
    unsigned flags = 0;
    const int k0 = wv * 196 + lane * 4;
    if (lane < 49) {
        float4 v = *(const float4*)(x + (size_t)row * 784 + k0);
        flags = (v.x != 0.0f ? 1u : 0u) | (v.y != 0.0f ? 2u : 0u) |
                (v.z != 0.0f ? 4u : 0u) | (v.w != 0.0f ? 8u : 0u);
    }
    const unsigned long long m0 = __ballot(flags & 1u);
    const unsigned long long m1 = __ballot(flags & 2u);
    const unsigned long long m2 = __ballot(flags & 4u);
    const unsigned long long m3 = __ballot(flags & 8u);
    const int c0 = __popcll(m0), c1 = __popcll(m1);
    const int c2 = __popcll(m2), c3 = __popcll(m3);
    if (lane == 0) cnt[wv] = c0 + c1 + c2 + c3;
    __syncthreads();
    int base = 0;
#pragma unroll
    for (int w = 0; w < 4; ++w) if (w < wv) base += cnt[w];
    const unsigned long long lm = ((unsigned long long)1 << lane) - 1;
    if (flags & 1u) list[base + __popcll(m0 & lm)] = (unsigned short)(k0 + 0);
    if (flags & 2u) list[base + c0 + __popcll(m1 & lm)] = (unsigned short)(k0 + 1);
    if (flags & 4u) list[base + c0 + c1 + __popcll(m2 & lm)] = (unsigned short)(k0 + 2);
    if (flags & 8u) list[base + c0 + c1 + c2 + __popcll(m3 & lm)] = (unsigned short)(k0 + 3);
    __syncthreads();
    const int n = cnt[0] + cnt[1] + cnt[2] + cnt[3];

    // ---- gather-accumulate ----
    float4 acc = {0.0f, 0.0f, 0.0f, 0.0f};
    const float* wbase = W1T + tid * 4;
    int i = 0;
    for (; i + 8 <= n; i += 8) {
        float4 w0 = *(const float4*)(wbase + (size_t)list[i + 0] * 1024);
        float4 w1 = *(const float4*)(wbase + (size_t)list[i + 1] * 1024);
        float4 w2 = *(const float4*)(wbase + (size_t)list[i + 2] * 1024);
        float4 w3 = *(const float4*)(wbase + (size_t)list[i + 3] * 1024);
        float4 w4 = *(const float4*)(wbase + (size_t)list[i + 4] * 1024);
        float4 w5 = *(const float4*)(wbase + (size_t)list[i + 5] * 1024);
        float4 w6 = *(const float4*)(wbase + (size_t)list[i + 6] * 1024);
        float4 w7 = *(const float4*)(wbase + (size_t)list[i + 7] * 1024);
        acc.x += ((w0.x + w1.x) + (w2.x + w3.x)) + ((w4.x + w5.x) + (w6.x + w7.x));
        acc.y += ((w0.y + w1.y) + (w2.y + w3.y)) + ((w4.y + w5.y) + (w6.y + w7.y));
        acc.z += ((w0.z + w1.z) + (w2.z + w3.z)) + ((w4.z + w5.z) + (w6.z + w7.z));
        acc.w += ((w0.w + w1.w) + (w2.w + w3.w)) + ((w4.w + w5.w) + (w6.w + w7.w));
    }
    for (; i < n; ++i) {
        float4 w0 = *(const float4*)(wbase + (size_t)list[i] * 1024);
        acc.x += w0.x; acc.y += w0.y; acc.z += w0.z; acc.w += w0.w;
    }
    *(float4*)(C1 + (size_t)row * 1024 + tid * 4) = acc;
}

// Layer-1 scan: ONE COLUMN per thread (262144 threads = 4 waves/SIMD; the
// float4 variant had only 1 wave/SIMD and was latency-exposed). Loads are
// recurrence-independent; unroll lets them issue ahead.
__global__ __launch_bounds__(256) void scan1(const float* __restrict__ C1,
                                             unsigned char* __restrict__ S1) {
    const int idx = blockIdx.x * 256 + threadIdx.x;   // 0..262143
    S1[idx] = 0;                                       // t = 0
    float I = 0.0f, V = 0.0f;
#pragma unroll 7
    for (int t = 1; t <= 98; ++t) {
        float c = C1[(size_t)(t - 1) * 262144 + idx];
        I = ALPHA_F * I + c;
        float Vp = BETA_F * V + ONE_MINUS_BETA_F * I;
        float s = (Vp > 1.0f) ? 1.0f : 0.0f;
        V = (1.0f - s) * Vp;
        S1[(size_t)t * 262144 + idx] = (unsigned char)s;
    }
}

// Layer-2 gather: one wave per row r of S1 (25344 rows), 4 rows per block.
// Lane reads 16 bytes of the spike row, bytes->bits via multiply trick,
// ballot-broadcast actives, gather W2T rows (lane owns 4 contiguous cols).
__global__ __launch_bounds__(256) void sparse2(const unsigned char* __restrict__ S1,
                                               const float* __restrict__ W2T,
                                               float* __restrict__ C2) {
    const int r = blockIdx.x * 4 + (threadIdx.x >> 6);
    const int lane = threadIdx.x & 63;
    uint4 sv = *(const uint4*)(S1 + (size_t)r * 1024 + lane * 16);
    // bytes are exactly 0/1: (v * 0x01020408) >> 24 packs them into 4 bits
    unsigned m16 = ((sv.x * 0x01020408u) >> 24) |
                   (((sv.y * 0x01020408u) >> 24) << 4) |
                   (((sv.z * 0x01020408u) >> 24) << 8) |
                   (((sv.w * 0x01020408u) >> 24) << 12);
    float4 acc = {0, 0, 0, 0};
#pragma unroll 1
    for (int j = 0; j < 16; ++j) {
        unsigned long long bm = __ballot((m16 >> j) & 1u);
        while (bm) {
            int L = __ffsll(bm) - 1;
            bm &= bm - 1;
            int k = L * 16 + j;
            float4 w = *(const float4*)(W2T + (size_t)k * 256 + lane * 4);
            acc.x += w.x; acc.y += w.y; acc.z += w.z; acc.w += w.w;
        }
    }
    *(float4*)(C2 + (size_t)r * 256 + lane * 4) = acc;
}

// Layer-2 scan: one thread per (b,n2), idx in [0, 65536). C2 rows t=0..98.
__global__ __launch_bounds__(256) void scan2(const float* __restrict__ C2,
                                             float* __restrict__ out) {
    const int idx = blockIdx.x * 256 + threadIdx.x;
    out[idx] = 0.0f;                                   // t = 0
    float I = 0.0f, V = 0.0f;
#pragma unroll 9
    for (int t = 1; t <= 99; ++t) {
        float c = C2[(size_t)(t - 1) * 65536 + idx];
        I = ALPHA_F * I + c;
        float Vp = BETA_F * V + ONE_MINUS_BETA_F * I;
        float s = (Vp > 1.0f) ? 1.0f : 0.0f;
        V = (1.0f - s) * Vp;
        out[(size_t)t * 65536 + idx] = s;
    }
}

extern "C" void kernel_launch(void* const* d_in, const int* in_sizes, int n_in,
                              void* d_out, int out_size, void* d_ws, size_t ws_size,
                              hipStream_t stream) {
    const float* x  = (const float*)d_in[0];   // [100,256,784] binary
    const float* W1 = (const float*)d_in[1];   // [1024,784]
    const float* W2 = (const float*)d_in[2];   // [256,1024]
    float* out = (float*)d_out;                // [100,256,256]

    // Workspace (~133 MB):
    //   C1   : 25088*1024*4 = 102,760,448 B   (C2 aliases C1; C1 dead after scan1)
    //   S1u8 : 25344*1024   =  25,952,256 B
    //   W1T  : 784*1024*4   =   3,211,264 B
    //   W2T  : 1024*256*4   =   1,048,576 B
    char* ws = (char*)d_ws;
    float* C1 = (float*)ws;
    unsigned char* S1 = (unsigned char*)(ws + (size_t)25088 * 1024 * 4);
    float* W1T = (float*)(ws + (size_t)25088 * 1024 * 4 + (size_t)25344 * 1024);
    float* W2T = W1T + (size_t)784 * 1024;
    float* C2 = C1;

    transpose_nt<<<dim3(25, 32), 256, 0, stream>>>(W1, W1T, 1024, 784);
    transpose_nt<<<dim3(32, 8), 256, 0, stream>>>(W2, W2T, 256, 1024);

    sparse1<<<25088, 256, 0, stream>>>(x, W1T, C1);
    scan1<<<1024, 256, 0, stream>>>(C1, S1);
    sparse2<<<25344 / 4, 256, 0, stream>>>(S1, W2T, C2);
    scan2<<<256, 256, 0, stream>>>(C2, out);
}

// Round 6
// 224.732 us; speedup vs baseline: 1.8782x; 1.3231x over previous
//
#include <hip/hip_runtime.h>
#include <hip/hip_bf16.h>

// SNN EventProp LIF forward, 2 layers: 784 -> 1024 -> 256, T=100, B=256.
//
// Structure: LIF current I is LINEAR in the matmul results -> all T matmuls
// of a layer collapse into one batched sparse op + per-(b,n) streaming scan.
// Both matmul inputs are BINARY spikes (x ~5%; layer-1 spikes rare), so each
// "GEMM" is a sparse gather-ADD of weight rows (fp32-exact, no multiplies).
//
// HARD-WON RULES:
//  - (r3+r4) never fuse the serial t-loop into gather kernels: grid
//    collapses to 1 wave/SIMD and goes latency-bound (2x regressions).
//  - (r5) in-kernel compaction costs ~35 us regardless of atomics-vs-ballot;
//    hoist it into its own tiny kernel so the hot gather kernel is pure VMEM.
//
//   precompact: per x-row active lists (cnt + int list), ballot-prefix
//   transpose W1 -> W1T [784,1024], W2 -> W2T [1024,256]
//   sparse1 : C1[25088,1024] = sum of W1T rows per list (8-deep float4 ILP)
//   scan1   : LIF scan, spikes emitted as BIT-PACKED u64 ballot words
//             S1b[99][4096] (3.2 MB instead of 26 MB uint8)
//   sparse2 : C2[25344,256]; per row read 16 uniform u64 mask words (128 B),
//             walk set bits in SALU, one float4 gather per spike
//   scan2   : out[100,256,256] (t=0 zero + t=1..99)
//
// ALPHA=0.8f, BETA=0.95f, 1-BETA=0.05f (exact float32 of the Python consts).

#define ALPHA_F 0.8f
#define BETA_F 0.95f
#define ONE_MINUS_BETA_F 0.05f

// WT[k*N + n] = W[n*K + k].  W: [N,K] row-major.
__global__ __launch_bounds__(256) void transpose_nt(const float* __restrict__ W,
                                                    float* __restrict__ WT,
                                                    int N, int K) {
    __shared__ float tile[32][33];
    const int k0 = blockIdx.x * 32, n0 = blockIdx.y * 32;
    const int tx = threadIdx.x & 31, ty = threadIdx.x >> 5;   // 32 x 8
#pragma unroll
    for (int r = 0; r < 4; ++r) {
        int n = n0 + ty + r * 8, k = k0 + tx;
        if (n < N && k < K) tile[ty + r * 8][tx] = W[(size_t)n * K + k];
    }
    __syncthreads();
#pragma unroll
    for (int r = 0; r < 4; ++r) {
        int k = k0 + ty + r * 8, n = n0 + tx;
        if (k < K && n < N) WT[(size_t)k * N + n] = tile[tx][ty + r * 8];
    }
}

// One wave per x-row r = t*256+b (t=0..97). Lanes 0..48 read one float4
// (49*4 = 196 float4 = 784 floats), ballot+popc prefix -> contiguous list
// in k-ascending order (same order as round-5 in-kernel compaction).
// lists stride 160 ints/row (mean actives 39.2, sigma 6.1; 160 is >19 sigma).
__global__ __launch_bounds__(256) void precompact(const float* __restrict__ x,
                                                  int* __restrict__ cnts,
                                                  int* __restrict__ lists) {
    const int r = blockIdx.x * 4 + (threadIdx.x >> 6);
    const int lane = threadIdx.x & 63;
    const int k0 = lane * 4;
    unsigned flags = 0;
    if (lane < 49) {
        float4 v = *(const float4*)(x + (size_t)r * 784 + k0);
        flags = (v.x != 0.0f ? 1u : 0u) | (v.y != 0.0f ? 2u : 0u) |
                (v.z != 0.0f ? 4u : 0u) | (v.w != 0.0f ? 8u : 0u);
    }
    const unsigned long long m0 = __ballot(flags & 1u);
    const unsigned long long m1 = __ballot(flags & 2u);
    const unsigned long long m2 = __ballot(flags & 4u);
    const unsigned long long m3 = __ballot(flags & 8u);
    const int c0 = __popcll(m0), c1 = __popcll(m1), c2 = __popcll(m2);
    const unsigned long long lm = ((unsigned long long)1 << lane) - 1;
    int* lrow = lists + (size_t)r * 160;
    if (flags & 1u) lrow[__popcll(m0 & lm)] = k0 + 0;
    if (flags & 2u) lrow[c0 + __popcll(m1 & lm)] = k0 + 1;
    if (flags & 4u) lrow[c0 + c1 + __popcll(m2 & lm)] = k0 + 2;
    if (flags & 8u) lrow[c0 + c1 + c2 + __popcll(m3 & lm)] = k0 + 3;
    if (lane == 0) cnts[r] = c0 + c1 + c2 + __popcll(m3);
}

// Layer-1 gather. One block per row; thread owns 4 contiguous cols.
// cnt/list accesses are block-uniform -> scalar (SMEM) loads; no LDS, no
// barriers, no flag VALU -- the loop is pure dwordx4 gather + adds.
__global__ __launch_bounds__(256) void sparse1(const int* __restrict__ cnts,
                                               const int* __restrict__ lists,
                                               const float* __restrict__ W1T,
                                               float* __restrict__ C1) {
    const int tid = threadIdx.x;
    const int row = blockIdx.x;
    const int n = cnts[row];
    const int* lst = lists + (size_t)row * 160;
    const float* wbase = W1T + tid * 4;
    float4 acc = {0.0f, 0.0f, 0.0f, 0.0f};
    int i = 0;
    for (; i + 8 <= n; i += 8) {   // 8 independent dwordx4 gathers in flight
        float4 w0 = *(const float4*)(wbase + (size_t)lst[i + 0] * 1024);
        float4 w1 = *(const float4*)(wbase + (size_t)lst[i + 1] * 1024);
        float4 w2 = *(const float4*)(wbase + (size_t)lst[i + 2] * 1024);
        float4 w3 = *(const float4*)(wbase + (size_t)lst[i + 3] * 1024);
        float4 w4 = *(const float4*)(wbase + (size_t)lst[i + 4] * 1024);
        float4 w5 = *(const float4*)(wbase + (size_t)lst[i + 5] * 1024);
        float4 w6 = *(const float4*)(wbase + (size_t)lst[i + 6] * 1024);
        float4 w7 = *(const float4*)(wbase + (size_t)lst[i + 7] * 1024);
        acc.x += ((w0.x + w1.x) + (w2.x + w3.x)) + ((w4.x + w5.x) + (w6.x + w7.x));
        acc.y += ((w0.y + w1.y) + (w2.y + w3.y)) + ((w4.y + w5.y) + (w6.y + w7.y));
        acc.z += ((w0.z + w1.z) + (w2.z + w3.z)) + ((w4.z + w5.z) + (w6.z + w7.z));
        acc.w += ((w0.w + w1.w) + (w2.w + w3.w)) + ((w4.w + w5.w) + (w6.w + w7.w));
    }
    for (; i < n; ++i) {
        float4 w0 = *(const float4*)(wbase + (size_t)lst[i] * 1024);
        acc.x += w0.x; acc.y += w0.y; acc.z += w0.z; acc.w += w0.w;
    }
    *(float4*)(C1 + (size_t)row * 1024 + tid * 4) = acc;
}

// Layer-1 scan: one col per thread (262144 threads = 4 waves/SIMD). Spikes
// exit as ballot-packed u64 words: S1b[t*4096 + (b*1024+n)/64].
__global__ __launch_bounds__(256) void scan1(const float* __restrict__ C1,
                                             unsigned long long* __restrict__ S1b) {
    const int idx = blockIdx.x * 256 + threadIdx.x;   // 0..262143
    const int word = idx >> 6;
    const int lane = threadIdx.x & 63;
    if (lane == 0) S1b[word] = 0ull;                   // t = 0
    float I = 0.0f, V = 0.0f;
#pragma unroll 7
    for (int t = 1; t <= 98; ++t) {
        float c = C1[(size_t)(t - 1) * 262144 + idx];
        I = ALPHA_F * I + c;
        float Vp = BETA_F * V + ONE_MINUS_BETA_F * I;
        const bool sp = Vp > 1.0f;
        unsigned long long m = __ballot(sp);
        V = sp ? 0.0f : Vp;
        if (lane == 0) S1b[(size_t)t * 4096 + word] = m;
    }
}

// Layer-2 gather: one wave per row r = t*256+b (25344 rows), 4 waves/block.
// Mask row = 16 u64 words at S1b + r*16 (wave-uniform -> scalar loads);
// walk set bits in SALU; one float4 gather per active presynaptic neuron.
__global__ __launch_bounds__(256) void sparse2(const unsigned long long* __restrict__ S1b,
                                               const float* __restrict__ W2T,
                                               float* __restrict__ C2) {
    const int r = __builtin_amdgcn_readfirstlane(blockIdx.x * 4 + (threadIdx.x >> 6));
    const int lane = threadIdx.x & 63;
    const unsigned long long* mrow = S1b + (size_t)r * 16;
    float4 acc = {0, 0, 0, 0};
#pragma unroll 1
    for (int j = 0; j < 16; ++j) {
        unsigned long long m = mrow[j];
        while (m) {
            const int bit = __ffsll((long long)m) - 1;
            m &= m - 1;
            const int k = j * 64 + bit;
            float4 w = *(const float4*)(W2T + (size_t)k * 256 + lane * 4);
            acc.x += w.x; acc.y += w.y; acc.z += w.z; acc.w += w.w;
        }
    }
    *(float4*)(C2 + (size_t)r * 256 + lane * 4) = acc;
}

// Layer-2 scan: one thread per (b,n2), idx in [0, 65536). C2 rows t=0..98.
__global__ __launch_bounds__(256) void scan2(const float* __restrict__ C2,
                                             float* __restrict__ out) {
    const int idx = blockIdx.x * 256 + threadIdx.x;
    out[idx] = 0.0f;                                   // t = 0
    float I = 0.0f, V = 0.0f;
#pragma unroll 9
    for (int t = 1; t <= 99; ++t) {
        float c = C2[(size_t)(t - 1) * 65536 + idx];
        I = ALPHA_F * I + c;
        float Vp = BETA_F * V + ONE_MINUS_BETA_F * I;
        float s = (Vp > 1.0f) ? 1.0f : 0.0f;
        V = (1.0f - s) * Vp;
        out[(size_t)t * 65536 + idx] = s;
    }
}

extern "C" void kernel_launch(void* const* d_in, const int* in_sizes, int n_in,
                              void* d_out, int out_size, void* d_ws, size_t ws_size,
                              hipStream_t stream) {
    const float* x  = (const float*)d_in[0];   // [100,256,784] binary
    const float* W1 = (const float*)d_in[1];   // [1024,784]
    const float* W2 = (const float*)d_in[2];   // [256,1024]
    float* out = (float*)d_out;                // [100,256,256]

    // Workspace (~126 MB, all offsets 8B-aligned):
    //   C1    @ 0          : 25088*1024*4 = 102,760,448   (C2 aliases C1)
    //   S1b   @ 102760448  : 99*4096*8    =   3,244,032
    //   W1T   @ 106004480  : 784*1024*4   =   3,211,264
    //   W2T   @ 109215744  : 1024*256*4   =   1,048,576
    //   cnts  @ 110264320  : 25088*4      =     100,352
    //   lists @ 110364672  : 25088*160*4  =  16,056,320   (end 126,420,992)
    char* ws = (char*)d_ws;
    float* C1 = (float*)ws;
    unsigned long long* S1b = (unsigned long long*)(ws + 102760448);
    float* W1T = (float*)(ws + 106004480);
    float* W2T = (float*)(ws + 109215744);
    int* cnts  = (int*)(ws + 110264320);
    int* lists = (int*)(ws + 110364672);
    float* C2 = C1;

    precompact<<<25088 / 4, 256, 0, stream>>>(x, cnts, lists);
    transpose_nt<<<dim3(25, 32), 256, 0, stream>>>(W1, W1T, 1024, 784);
    transpose_nt<<<dim3(32, 8), 256, 0, stream>>>(W2, W2T, 256, 1024);

    sparse1<<<25088, 256, 0, stream>>>(cnts, lists, W1T, C1);
    scan1<<<1024, 256, 0, stream>>>(C1, S1b);
    sparse2<<<25344 / 4, 256, 0, stream>>>(S1b, W2T, C2);
    scan2<<<256, 256, 0, stream>>>(C2, out);
}